// Round 12
// baseline (182.998 us; speedup 1.0000x reference)
//
#include <hip/hip_runtime.h>
#include <hip/hip_bf16.h>
#include <stdint.h>

#define NN 8192
#define DIN 512
#define HH 256
#define EE 262144
#define CAP 96
#define LN_EPS 1e-5f

typedef __attribute__((ext_vector_type(8))) short bf16x8;
typedef __attribute__((ext_vector_type(4))) short s16x4;
typedef __attribute__((ext_vector_type(4))) float f32x4;

__device__ __forceinline__ short f2bf_bits(float x) {
    __hip_bfloat16 b = __float2bfloat16(x);
    return __builtin_bit_cast(short, b);
}
__device__ __forceinline__ float bf2f(short s) {
    uint32_t u = ((uint32_t)(uint16_t)s) << 16;
    return __builtin_bit_cast(float, u);
}
__device__ __forceinline__ void load16_lds(const void* g, void* l) {
    __builtin_amdgcn_global_load_lds((const __attribute__((address_space(1))) uint32_t*)g,
                                     (__attribute__((address_space(3))) uint32_t*)l, 16, 0, 0);
}

// ---------------- prep: zero accumulators/cnt/emb, convert W_in/W_gat/X to bf16 ----------------
#define NW1 (HH * DIN)
#define NW2 (2 * HH * HH)
#define NX (NN * DIN)
#define ZCOUNT (2 * (2 * NN + HH) + NN)   // s1/s2/St x2 layers + cnt
__global__ __launch_bounds__(256) void prep(const float* __restrict__ W_in, __hip_bfloat16* __restrict__ Wb_in,
                                            const float* __restrict__ W_gat, __hip_bfloat16* __restrict__ Wgb,
                                            const float* __restrict__ X, __hip_bfloat16* __restrict__ Xb,
                                            float* __restrict__ zbase, float* __restrict__ emb) {
    int gtid = blockIdx.x * 256 + threadIdx.x;
    if (gtid < ZCOUNT) ((int*)zbase)[gtid] = 0;
    if (gtid < HH) emb[gtid] = 0.f;
    int q = gtid * 4;
    const float* x;
    __hip_bfloat16* y;
    int b;
    if (q < NW1) { x = W_in; y = Wb_in; b = q; }
    else if (q < NW1 + NW2) { x = W_gat; y = Wgb; b = q - NW1; }
    else if (q < NW1 + NW2 + NX) { x = X; y = Xb; b = q - NW1 - NW2; }
    else return;
    float4 v = *(const float4*)(x + b);
    y[b + 0] = __float2bfloat16(v.x);
    y[b + 1] = __float2bfloat16(v.y);
    y[b + 2] = __float2bfloat16(v.z);
    y[b + 3] = __float2bfloat16(v.w);
}

// ---------------- bucketed adjacency fill, 2 edges/thread ----------------
__global__ void fill_buckets(const int* __restrict__ src, const int* __restrict__ tgt,
                             int* __restrict__ cnt, int* __restrict__ buck) {
    int k = (blockIdx.x * 256 + threadIdx.x) * 2;
    if (k < EE) {
        int2 sv = *(const int2*)(src + k);
        int2 tv = *(const int2*)(tgt + k);
        int p = atomicAdd(&cnt[sv.x], 1);
        if (p < CAP) buck[sv.x * CAP + p] = tv.x;
        p = atomicAdd(&cnt[sv.y], 1);
        if (p < CAP) buck[sv.y * CAP + p] = tv.y;
    }
}

// ---------------- bf16 GEMM + bias: C_bf16 = A @ B^T + bias ----------------
__global__ __launch_bounds__(256) void gemm_bb_bias(const __hip_bfloat16* __restrict__ A,
                                                    const __hip_bfloat16* __restrict__ B,
                                                    const float* __restrict__ bias,
                                                    __hip_bfloat16* __restrict__ Cb,
                                                    int Nc, int K) {
    __shared__ __hip_bfloat16 As[64 * 32];
    __shared__ __hip_bfloat16 Bs[64 * 32];
    const int tid = threadIdx.x;
    const int row0 = blockIdx.y * 64, col0 = blockIdx.x * 64;
    const int w = tid >> 6, l = tid & 63;
    const int quad = l >> 4, r = l & 15;
    const int mh = (w & 1) * 32, nh = (w >> 1) * 32;
    f32x4 acc[2][2] = {};

    const int srow = tid >> 2, scol = (tid & 3) * 8;
    const __hip_bfloat16* gA = A + (size_t)(row0 + srow) * K + scol;
    const __hip_bfloat16* gB = B + (size_t)(col0 + srow) * K + scol;
    __hip_bfloat16* lA = &As[tid * 8];
    __hip_bfloat16* lB = &Bs[tid * 8];

    for (int k0 = 0; k0 < K; k0 += 32) {
        load16_lds(gA + k0, lA);
        load16_lds(gB + k0, lB);
        __syncthreads();
        bf16x8 aF[2], bF[2];
#pragma unroll
        for (int mi = 0; mi < 2; mi++)
            aF[mi] = *(const bf16x8*)&As[(mh + mi * 16 + r) * 32 + quad * 8];
#pragma unroll
        for (int ni = 0; ni < 2; ni++)
            bF[ni] = *(const bf16x8*)&Bs[(nh + ni * 16 + r) * 32 + quad * 8];
#pragma unroll
        for (int mi = 0; mi < 2; mi++)
#pragma unroll
            for (int ni = 0; ni < 2; ni++)
                acc[mi][ni] = __builtin_amdgcn_mfma_f32_16x16x32_bf16(aF[mi], bF[ni], acc[mi][ni], 0, 0, 0);
        __syncthreads();
    }

#pragma unroll
    for (int mi = 0; mi < 2; mi++)
#pragma unroll
        for (int ni = 0; ni < 2; ni++) {
            int gcol = col0 + nh + ni * 16 + r;
            float bv = bias[gcol];
#pragma unroll
            for (int reg = 0; reg < 4; reg++) {
                int grow = row0 + mh + mi * 16 + quad * 4 + reg;
                Cb[(size_t)grow * Nc + gcol] = __float2bfloat16(acc[mi][ni][reg] + bv);
            }
        }
}

// ---------------- layer GEMM + fused score epilogue ----------------
__global__ __launch_bounds__(256) void gemm_bb_score(const __hip_bfloat16* __restrict__ A,
                                                     const __hip_bfloat16* __restrict__ B,
                                                     __hip_bfloat16* __restrict__ Cb,
                                                     const float* __restrict__ ag1,
                                                     const float* __restrict__ ag2,
                                                     float* __restrict__ s1, float* __restrict__ s2,
                                                     float* __restrict__ St,
                                                     int Nc, int K) {
    __shared__ __hip_bfloat16 As[64 * 32];
    __shared__ __hip_bfloat16 Bs[64 * 32];
    const int tid = threadIdx.x;
    const int row0 = blockIdx.y * 64, col0 = blockIdx.x * 64;
    const int w = tid >> 6, l = tid & 63;
    const int quad = l >> 4, r = l & 15;
    const int mh = (w & 1) * 32, nh = (w >> 1) * 32;
    f32x4 acc[2][2] = {};

    const int srow = tid >> 2, scol = (tid & 3) * 8;
    const __hip_bfloat16* gA = A + (size_t)(row0 + srow) * K + scol;
    const __hip_bfloat16* gB = B + (size_t)(col0 + srow) * K + scol;
    __hip_bfloat16* lA = &As[tid * 8];
    __hip_bfloat16* lB = &Bs[tid * 8];

    for (int k0 = 0; k0 < K; k0 += 32) {
        load16_lds(gA + k0, lA);
        load16_lds(gB + k0, lB);
        __syncthreads();
        bf16x8 aF[2], bF[2];
#pragma unroll
        for (int mi = 0; mi < 2; mi++)
            aF[mi] = *(const bf16x8*)&As[(mh + mi * 16 + r) * 32 + quad * 8];
#pragma unroll
        for (int ni = 0; ni < 2; ni++)
            bF[ni] = *(const bf16x8*)&Bs[(nh + ni * 16 + r) * 32 + quad * 8];
#pragma unroll
        for (int mi = 0; mi < 2; mi++)
#pragma unroll
            for (int ni = 0; ni < 2; ni++)
                acc[mi][ni] = __builtin_amdgcn_mfma_f32_16x16x32_bf16(aF[mi], bF[ni], acc[mi][ni], 0, 0, 0);
        __syncthreads();
    }

#pragma unroll
    for (int mi = 0; mi < 2; mi++)
#pragma unroll
        for (int ni = 0; ni < 2; ni++) {
            int gcol = col0 + nh + ni * 16 + r;
#pragma unroll
            for (int reg = 0; reg < 4; reg++) {
                int grow = row0 + mh + mi * 16 + quad * 4 + reg;
                Cb[(size_t)grow * Nc + gcol] = __float2bfloat16(acc[mi][ni][reg]);
            }
        }

    float a1v[2], a2v[2];
#pragma unroll
    for (int ni = 0; ni < 2; ni++) {
        int gcol = col0 + nh + ni * 16 + r;
        a1v[ni] = ag1[gcol];
        a2v[ni] = ag2[gcol];
    }
#pragma unroll
    for (int mi = 0; mi < 2; mi++)
#pragma unroll
        for (int reg = 0; reg < 4; reg++) {
            float p1 = acc[mi][0][reg] * a1v[0] + acc[mi][1][reg] * a1v[1];
            float p2 = acc[mi][0][reg] * a2v[0] + acc[mi][1][reg] * a2v[1];
#pragma unroll
            for (int off = 1; off <= 8; off <<= 1) {
                p1 += __shfl_xor(p1, off);
                p2 += __shfl_xor(p2, off);
            }
            if (r == 0) {
                int grow = row0 + mh + mi * 16 + quad * 4 + reg;
                atomicAdd(&s1[grow], p1);
                atomicAdd(&s2[grow], p2);
            }
        }
#pragma unroll
    for (int ni = 0; ni < 2; ni++) {
        float pS = 0.f;
#pragma unroll
        for (int mi = 0; mi < 2; mi++)
#pragma unroll
            for (int reg = 0; reg < 4; reg++) pS += acc[mi][ni][reg];
        pS += __shfl_xor(pS, 16);
        pS += __shfl_xor(pS, 32);
        if (quad == 0) atomicAdd(&St[col0 + nh + ni * 16 + r], pS);
    }
}

// ---------------- wave-per-row GAT, 4-way edge split: 4 gathers in flight, 2x16B/lane ----------------
// quarter qt = lane>>4 processes edges 4j+qt; lane owns channels 16*(lane&15)..+15
__global__ __launch_bounds__(256) void gat_row(const __hip_bfloat16* __restrict__ hprev,
                                               const __hip_bfloat16* __restrict__ hw,
                                               const int* __restrict__ cnt, const int* __restrict__ buck,
                                               const float* __restrict__ s1, const float* __restrict__ s2,
                                               const float* __restrict__ St,
                                               const float* __restrict__ lng, const float* __restrict__ lnb,
                                               const float* __restrict__ W_pool, const float* __restrict__ b_pool,
                                               float* __restrict__ houtf, __hip_bfloat16* __restrict__ houtb,
                                               float* __restrict__ gate, int last) {
    const int wv = threadIdx.x >> 6, lane = threadIdx.x & 63;
    const int qt = lane >> 4, sl = lane & 15;
    const int i = blockIdx.x * 4 + wv;
    const int deg = cnt[i];
    const int base = i * CAP;
    const float s1i = s1[i];
    const short* hws = (const short*)hw;

    float u[16] = {};
    float lsum = 0.f;

    for (int kb = 0; kb < deg; kb += 64) {
        int k = kb + lane;
        float wk = 0.f;
        int ck = 0;
        if (k < deg) {
            int j = buck[base + k];
            float e = s1i + s2[j];
            e = e > 0.f ? e : 0.2f * e;
            wk = __expf(e) - 1.f;
            ck = j;
        }
        lsum += wk;
        int nb = min(64, deg - kb);
        int nquad = (nb + 3) >> 2;
#pragma unroll 2
        for (int jj = 0; jj < nquad; jj++) {
            float wj = __shfl(wk, 4 * jj + qt);
            int cj = __shfl(ck, 4 * jj + qt);
            const short* rp = hws + (size_t)cj * HH + 16 * sl;
            bf16x8 hv0 = *(const bf16x8*)rp;
            bf16x8 hv1 = *(const bf16x8*)(rp + 8);
#pragma unroll
            for (int q = 0; q < 8; q++) {
                u[q] += wj * bf2f(hv0[q]);
                u[8 + q] += wj * bf2f(hv1[q]);
            }
        }
    }
    // combine quarters: lanes sl, sl+16, sl+32, sl+48 own same channels
#pragma unroll
    for (int q = 0; q < 16; q++) {
        u[q] += __shfl_xor(u[q], 16);
        u[q] += __shfl_xor(u[q], 32);
    }
    // lsum over all 64 lanes
#pragma unroll
    for (int off = 32; off; off >>= 1) lsum += __shfl_xor(lsum, off);
    const float inv = 1.f / ((float)NN + lsum);

    float Sts[16], x[16];
#pragma unroll
    for (int q = 0; q < 4; q++) {
        float4 sv = *(const float4*)(St + 16 * sl + 4 * q);
        Sts[4 * q + 0] = sv.x; Sts[4 * q + 1] = sv.y; Sts[4 * q + 2] = sv.z; Sts[4 * q + 3] = sv.w;
    }
    bf16x8 hp0 = *(const bf16x8*)((const short*)hprev + (size_t)i * HH + 16 * sl);
    bf16x8 hp1 = *(const bf16x8*)((const short*)hprev + (size_t)i * HH + 16 * sl + 8);
    float part = 0.f;
#pragma unroll
    for (int q = 0; q < 8; q++) {
        x[q] = bf2f(hp0[q]) + (Sts[q] + u[q]) * inv;
        x[8 + q] = bf2f(hp1[q]) + (Sts[8 + q] + u[8 + q]) * inv;
    }
#pragma unroll
    for (int q = 0; q < 16; q++) part += x[q];
    // 16-lane butterfly: each quarter-group has all 256 channels
#pragma unroll
    for (int off = 8; off; off >>= 1) part += __shfl_xor(part, off);
    float mu = part * (1.f / HH);
    float d[16];
    float vs = 0.f;
#pragma unroll
    for (int q = 0; q < 16; q++) { d[q] = x[q] - mu; vs += d[q] * d[q]; }
#pragma unroll
    for (int off = 8; off; off >>= 1) vs += __shfl_xor(vs, off);
    float rstd = rsqrtf(vs * (1.f / HH) + LN_EPS);
    float gg[16], bv[16];
#pragma unroll
    for (int q = 0; q < 4; q++) {
        float4 gv = *(const float4*)(lng + 16 * sl + 4 * q);
        float4 bb = *(const float4*)(lnb + 16 * sl + 4 * q);
        gg[4 * q + 0] = gv.x; gg[4 * q + 1] = gv.y; gg[4 * q + 2] = gv.z; gg[4 * q + 3] = gv.w;
        bv[4 * q + 0] = bb.x; bv[4 * q + 1] = bb.y; bv[4 * q + 2] = bb.z; bv[4 * q + 3] = bb.w;
    }
    float y[16];
#pragma unroll
    for (int q = 0; q < 16; q++) {
        float t = d[q] * rstd * gg[q] + bv[q];
        y[q] = t > 0.f ? t : __expf(t) - 1.f;
    }

    // stores: quarter qt writes channels 16*sl + 4*qt .. +3 (quarters hold identical y)
    const int co = 16 * sl + 4 * qt;
    if (houtb) {
        s16x4 yv;
#pragma unroll
        for (int q = 0; q < 4; q++) yv[q] = f2bf_bits(y[4 * qt + q]);
        *(s16x4*)((short*)houtb + (size_t)i * HH + co) = yv;
    }
    if (houtf) {
        float4 yf = { y[4 * qt], y[4 * qt + 1], y[4 * qt + 2], y[4 * qt + 3] };
        *(float4*)(houtf + (size_t)i * HH + co) = yf;
    }

    if (last) {
        float p = 0.f;
#pragma unroll
        for (int q = 0; q < 4; q++) {
            float4 wv4 = *(const float4*)(W_pool + 16 * sl + 4 * q);
            p += y[4 * q + 0] * 0.f; // placeholder avoided; see below
        }
        // recompute cleanly: dot over this lane's 16 channels
        p = 0.f;
#pragma unroll
        for (int q = 0; q < 4; q++) {
            float4 wv4 = *(const float4*)(W_pool + 16 * sl + 4 * q);
            p += y[4 * q + 0] * wv4.x + y[4 * q + 1] * wv4.y + y[4 * q + 2] * wv4.z + y[4 * q + 3] * wv4.w;
        }
#pragma unroll
        for (int off = 8; off; off >>= 1) p += __shfl_xor(p, off);
        if (lane == 0) gate[i] = 1.f / (1.f + __expf(-(p + b_pool[0])));
    }
}

// ---------------- pooling: 256 blocks x 32 rows (256 atomics/address) ----------------
__global__ __launch_bounds__(256) void pool_kernel(const float* __restrict__ h, const float* __restrict__ gate,
                                                   float* __restrict__ emb) {
    int c = threadIdx.x;
    int r0 = blockIdx.x * 32;
    float acc = 0.f;
#pragma unroll
    for (int rr = 0; rr < 32; rr++) {
        int r = r0 + rr;
        acc += gate[r] * h[(size_t)r * HH + c];
    }
    atomicAdd(&emb[c], acc);
}

extern "C" void kernel_launch(void* const* d_in, const int* in_sizes, int n_in,
                              void* d_out, int out_size, void* d_ws, size_t ws_size,
                              hipStream_t stream) {
    const float* X      = (const float*)d_in[0];
    const int*   ei     = (const int*)d_in[1];
    const float* W_in   = (const float*)d_in[2];
    const float* b_in   = (const float*)d_in[3];
    const float* W_gat  = (const float*)d_in[4];
    const float* a_gat  = (const float*)d_in[5];
    const float* ln_g   = (const float*)d_in[6];
    const float* ln_b   = (const float*)d_in[7];
    const float* W_pool = (const float*)d_in[8];
    const float* b_pool = (const float*)d_in[9];
    float* out = (float*)d_out;

    // ws layout: bf16 region, then zero-init fp32/int block, then gate/buckets
    __hip_bfloat16* hb    = (__hip_bfloat16*)d_ws;            // NN*HH
    __hip_bfloat16* hwb   = hb + (size_t)NN * HH;             // NN*HH
    __hip_bfloat16* Wb_in = hwb + (size_t)NN * HH;            // HH*DIN
    __hip_bfloat16* Wgb   = Wb_in + (size_t)HH * DIN;         // 2*HH*HH
    __hip_bfloat16* Xb    = Wgb + (size_t)2 * HH * HH;        // NN*DIN
    float* zbase = (float*)(Xb + (size_t)NN * DIN);
    float* s1_0 = zbase;                 // NN
    float* s2_0 = s1_0 + NN;             // NN
    float* St_0 = s2_0 + NN;             // HH
    float* s1_1 = St_0 + HH;             // NN
    float* s2_1 = s1_1 + NN;             // NN
    float* St_1 = s2_1 + NN;             // HH
    int* cnt  = (int*)(St_1 + HH);       // NN  (zeroed in prep)
    float* gate = (float*)(cnt + NN);    // NN
    int* buck = (int*)(gate + NN);       // NN*CAP

    const int* src = ei;
    const int* tgt = ei + EE;
    float* emb = out + (size_t)NN * HH;

    // prep: zero + all bf16 conversions (one dispatch)
    int prep_quads = (NW1 + NW2 + NX) / 4;
    prep<<<(prep_quads + 255) / 256, 256, 0, stream>>>(W_in, Wb_in, W_gat, Wgb, X, Xb, zbase, emb);

    // adjacency buckets (one dispatch)
    fill_buckets<<<EE / 512, 256, 0, stream>>>(src, tgt, cnt, buck);

    // h = X @ W_in^T + b_in
    gemm_bb_bias<<<dim3(HH / 64, NN / 64), 256, 0, stream>>>(Xb, Wb_in, b_in, hb, HH, DIN);

    for (int ll = 0; ll < 2; ll++) {
        float* s1 = ll ? s1_1 : s1_0;
        float* s2 = ll ? s2_1 : s2_0;
        float* St = ll ? St_1 : St_0;
        const float* ag = a_gat + (size_t)ll * 2 * HH;
        gemm_bb_score<<<dim3(HH / 64, NN / 64), 256, 0, stream>>>(hb, Wgb + (size_t)ll * HH * HH, hwb,
                                                                  ag, ag + HH, s1, s2, St, HH, HH);
        gat_row<<<NN / 4, 256, 0, stream>>>(hb, hwb, cnt, buck, s1, s2, St,
                                            ln_g + (size_t)ll * HH, ln_b + (size_t)ll * HH,
                                            W_pool, b_pool,
                                            (ll == 1) ? out : nullptr,
                                            (ll == 0) ? hb : nullptr,
                                            gate, ll);
    }

    pool_kernel<<<NN / 32, 256, 0, stream>>>(out, gate, emb);
}

// Round 13
// 177.266 us; speedup vs baseline: 1.0323x; 1.0323x over previous
//
#include <hip/hip_runtime.h>
#include <hip/hip_bf16.h>
#include <stdint.h>

#define NN 8192
#define DIN 512
#define HH 256
#define EE 262144
#define CAP 96
#define LN_EPS 1e-5f

typedef __attribute__((ext_vector_type(8))) short bf16x8;
typedef __attribute__((ext_vector_type(4))) short s16x4;
typedef __attribute__((ext_vector_type(4))) float f32x4;

__device__ __forceinline__ short f2bf_bits(float x) {
    __hip_bfloat16 b = __float2bfloat16(x);
    return __builtin_bit_cast(short, b);
}
__device__ __forceinline__ float bf2f(short s) {
    uint32_t u = ((uint32_t)(uint16_t)s) << 16;
    return __builtin_bit_cast(float, u);
}
__device__ __forceinline__ void load16_lds(const void* g, void* l) {
    __builtin_amdgcn_global_load_lds((const __attribute__((address_space(1))) uint32_t*)g,
                                     (__attribute__((address_space(3))) uint32_t*)l, 16, 0, 0);
}

// ---------------- prep: zero accumulators/cnt/emb, convert W_in/W_gat/X to bf16 ----------------
#define NW1 (HH * DIN)
#define NW2 (2 * HH * HH)
#define NX (NN * DIN)
#define ZCOUNT (2 * (2 * NN + HH) + NN)   // s1/s2/St x2 layers + cnt
__global__ __launch_bounds__(256) void prep(const float* __restrict__ W_in, __hip_bfloat16* __restrict__ Wb_in,
                                            const float* __restrict__ W_gat, __hip_bfloat16* __restrict__ Wgb,
                                            const float* __restrict__ X, __hip_bfloat16* __restrict__ Xb,
                                            float* __restrict__ zbase, float* __restrict__ emb) {
    int gtid = blockIdx.x * 256 + threadIdx.x;
    if (gtid < ZCOUNT) ((int*)zbase)[gtid] = 0;
    if (gtid < HH) emb[gtid] = 0.f;
    int q = gtid * 4;
    const float* x;
    __hip_bfloat16* y;
    int b;
    if (q < NW1) { x = W_in; y = Wb_in; b = q; }
    else if (q < NW1 + NW2) { x = W_gat; y = Wgb; b = q - NW1; }
    else if (q < NW1 + NW2 + NX) { x = X; y = Xb; b = q - NW1 - NW2; }
    else return;
    float4 v = *(const float4*)(x + b);
    y[b + 0] = __float2bfloat16(v.x);
    y[b + 1] = __float2bfloat16(v.y);
    y[b + 2] = __float2bfloat16(v.z);
    y[b + 3] = __float2bfloat16(v.w);
}

// ---------------- bucketed adjacency fill, 2 edges/thread ----------------
__global__ void fill_buckets(const int* __restrict__ src, const int* __restrict__ tgt,
                             int* __restrict__ cnt, int* __restrict__ buck) {
    int k = (blockIdx.x * 256 + threadIdx.x) * 2;
    if (k < EE) {
        int2 sv = *(const int2*)(src + k);
        int2 tv = *(const int2*)(tgt + k);
        int p = atomicAdd(&cnt[sv.x], 1);
        if (p < CAP) buck[sv.x * CAP + p] = tv.x;
        p = atomicAdd(&cnt[sv.y], 1);
        if (p < CAP) buck[sv.y * CAP + p] = tv.y;
    }
}

// ---------------- bf16 GEMM + bias: C_bf16 = A @ B^T + bias ----------------
__global__ __launch_bounds__(256) void gemm_bb_bias(const __hip_bfloat16* __restrict__ A,
                                                    const __hip_bfloat16* __restrict__ B,
                                                    const float* __restrict__ bias,
                                                    __hip_bfloat16* __restrict__ Cb,
                                                    int Nc, int K) {
    __shared__ __hip_bfloat16 As[64 * 32];
    __shared__ __hip_bfloat16 Bs[64 * 32];
    const int tid = threadIdx.x;
    const int row0 = blockIdx.y * 64, col0 = blockIdx.x * 64;
    const int w = tid >> 6, l = tid & 63;
    const int quad = l >> 4, r = l & 15;
    const int mh = (w & 1) * 32, nh = (w >> 1) * 32;
    f32x4 acc[2][2] = {};

    const int srow = tid >> 2, scol = (tid & 3) * 8;
    const __hip_bfloat16* gA = A + (size_t)(row0 + srow) * K + scol;
    const __hip_bfloat16* gB = B + (size_t)(col0 + srow) * K + scol;
    __hip_bfloat16* lA = &As[tid * 8];
    __hip_bfloat16* lB = &Bs[tid * 8];

    for (int k0 = 0; k0 < K; k0 += 32) {
        load16_lds(gA + k0, lA);
        load16_lds(gB + k0, lB);
        __syncthreads();
        bf16x8 aF[2], bF[2];
#pragma unroll
        for (int mi = 0; mi < 2; mi++)
            aF[mi] = *(const bf16x8*)&As[(mh + mi * 16 + r) * 32 + quad * 8];
#pragma unroll
        for (int ni = 0; ni < 2; ni++)
            bF[ni] = *(const bf16x8*)&Bs[(nh + ni * 16 + r) * 32 + quad * 8];
#pragma unroll
        for (int mi = 0; mi < 2; mi++)
#pragma unroll
            for (int ni = 0; ni < 2; ni++)
                acc[mi][ni] = __builtin_amdgcn_mfma_f32_16x16x32_bf16(aF[mi], bF[ni], acc[mi][ni], 0, 0, 0);
        __syncthreads();
    }

#pragma unroll
    for (int mi = 0; mi < 2; mi++)
#pragma unroll
        for (int ni = 0; ni < 2; ni++) {
            int gcol = col0 + nh + ni * 16 + r;
            float bv = bias[gcol];
#pragma unroll
            for (int reg = 0; reg < 4; reg++) {
                int grow = row0 + mh + mi * 16 + quad * 4 + reg;
                Cb[(size_t)grow * Nc + gcol] = __float2bfloat16(acc[mi][ni][reg] + bv);
            }
        }
}

// ---------------- layer GEMM + fused score epilogue ----------------
__global__ __launch_bounds__(256) void gemm_bb_score(const __hip_bfloat16* __restrict__ A,
                                                     const __hip_bfloat16* __restrict__ B,
                                                     __hip_bfloat16* __restrict__ Cb,
                                                     const float* __restrict__ ag1,
                                                     const float* __restrict__ ag2,
                                                     float* __restrict__ s1, float* __restrict__ s2,
                                                     float* __restrict__ St,
                                                     int Nc, int K) {
    __shared__ __hip_bfloat16 As[64 * 32];
    __shared__ __hip_bfloat16 Bs[64 * 32];
    const int tid = threadIdx.x;
    const int row0 = blockIdx.y * 64, col0 = blockIdx.x * 64;
    const int w = tid >> 6, l = tid & 63;
    const int quad = l >> 4, r = l & 15;
    const int mh = (w & 1) * 32, nh = (w >> 1) * 32;
    f32x4 acc[2][2] = {};

    const int srow = tid >> 2, scol = (tid & 3) * 8;
    const __hip_bfloat16* gA = A + (size_t)(row0 + srow) * K + scol;
    const __hip_bfloat16* gB = B + (size_t)(col0 + srow) * K + scol;
    __hip_bfloat16* lA = &As[tid * 8];
    __hip_bfloat16* lB = &Bs[tid * 8];

    for (int k0 = 0; k0 < K; k0 += 32) {
        load16_lds(gA + k0, lA);
        load16_lds(gB + k0, lB);
        __syncthreads();
        bf16x8 aF[2], bF[2];
#pragma unroll
        for (int mi = 0; mi < 2; mi++)
            aF[mi] = *(const bf16x8*)&As[(mh + mi * 16 + r) * 32 + quad * 8];
#pragma unroll
        for (int ni = 0; ni < 2; ni++)
            bF[ni] = *(const bf16x8*)&Bs[(nh + ni * 16 + r) * 32 + quad * 8];
#pragma unroll
        for (int mi = 0; mi < 2; mi++)
#pragma unroll
            for (int ni = 0; ni < 2; ni++)
                acc[mi][ni] = __builtin_amdgcn_mfma_f32_16x16x32_bf16(aF[mi], bF[ni], acc[mi][ni], 0, 0, 0);
        __syncthreads();
    }

#pragma unroll
    for (int mi = 0; mi < 2; mi++)
#pragma unroll
        for (int ni = 0; ni < 2; ni++) {
            int gcol = col0 + nh + ni * 16 + r;
#pragma unroll
            for (int reg = 0; reg < 4; reg++) {
                int grow = row0 + mh + mi * 16 + quad * 4 + reg;
                Cb[(size_t)grow * Nc + gcol] = __float2bfloat16(acc[mi][ni][reg]);
            }
        }

    float a1v[2], a2v[2];
#pragma unroll
    for (int ni = 0; ni < 2; ni++) {
        int gcol = col0 + nh + ni * 16 + r;
        a1v[ni] = ag1[gcol];
        a2v[ni] = ag2[gcol];
    }
#pragma unroll
    for (int mi = 0; mi < 2; mi++)
#pragma unroll
        for (int reg = 0; reg < 4; reg++) {
            float p1 = acc[mi][0][reg] * a1v[0] + acc[mi][1][reg] * a1v[1];
            float p2 = acc[mi][0][reg] * a2v[0] + acc[mi][1][reg] * a2v[1];
#pragma unroll
            for (int off = 1; off <= 8; off <<= 1) {
                p1 += __shfl_xor(p1, off);
                p2 += __shfl_xor(p2, off);
            }
            if (r == 0) {
                int grow = row0 + mh + mi * 16 + quad * 4 + reg;
                atomicAdd(&s1[grow], p1);
                atomicAdd(&s2[grow], p2);
            }
        }
#pragma unroll
    for (int ni = 0; ni < 2; ni++) {
        float pS = 0.f;
#pragma unroll
        for (int mi = 0; mi < 2; mi++)
#pragma unroll
            for (int reg = 0; reg < 4; reg++) pS += acc[mi][ni][reg];
        pS += __shfl_xor(pS, 16);
        pS += __shfl_xor(pS, 32);
        if (quad == 0) atomicAdd(&St[col0 + nh + ni * 16 + r], pS);
    }
}

// ---------------- wave-per-row GAT, lane-split: 2 edges in flight, 16B gathers ----------------
// lane = 64 lanes; half = lane>>5 processes even/odd edges; lane owns channels 8*(lane&31)..+7
__global__ __launch_bounds__(256) void gat_row(const __hip_bfloat16* __restrict__ hprev,
                                               const __hip_bfloat16* __restrict__ hw,
                                               const int* __restrict__ cnt, const int* __restrict__ buck,
                                               const float* __restrict__ s1, const float* __restrict__ s2,
                                               const float* __restrict__ St,
                                               const float* __restrict__ lng, const float* __restrict__ lnb,
                                               const float* __restrict__ W_pool, const float* __restrict__ b_pool,
                                               float* __restrict__ houtf, __hip_bfloat16* __restrict__ houtb,
                                               float* __restrict__ gate, int last) {
    const int wv = threadIdx.x >> 6, lane = threadIdx.x & 63;
    const int half = lane >> 5, sl = lane & 31;
    const int i = blockIdx.x * 4 + wv;
    const int deg = cnt[i];
    const int base = i * CAP;
    const float s1i = s1[i];
    const short* hws = (const short*)hw;

    float u[8] = {};
    float lsum = 0.f;

    for (int kb = 0; kb < deg; kb += 64) {
        int k = kb + lane;
        float wk = 0.f;
        int ck = 0;
        if (k < deg) {
            int j = buck[base + k];
            float e = s1i + s2[j];
            e = e > 0.f ? e : 0.2f * e;
            wk = __expf(e) - 1.f;
            ck = j;
        }
        lsum += wk;
        int nb = min(64, deg - kb);
        int npair = (nb + 1) >> 1;
#pragma unroll 4
        for (int jj = 0; jj < npair; jj++) {
            float wj = __shfl(wk, 2 * jj + half);
            int cj = __shfl(ck, 2 * jj + half);
            bf16x8 hv = *(const bf16x8*)(hws + (size_t)cj * HH + 8 * sl);
#pragma unroll
            for (int q = 0; q < 8; q++) u[q] += wj * bf2f(hv[q]);
        }
    }
    // combine even/odd halves (each lane pair (sl, sl+32) covers same channels)
#pragma unroll
    for (int q = 0; q < 8; q++) u[q] += __shfl_xor(u[q], 32);
    // lsum over all 64 lanes
#pragma unroll
    for (int off = 32; off; off >>= 1) lsum += __shfl_xor(lsum, off);
    const float inv = 1.f / ((float)NN + lsum);

    float4 Sa = *(const float4*)(St + 8 * sl);
    float4 Sb = *(const float4*)(St + 8 * sl + 4);
    float Sts[8] = { Sa.x, Sa.y, Sa.z, Sa.w, Sb.x, Sb.y, Sb.z, Sb.w };
    bf16x8 hp = *(const bf16x8*)((const short*)hprev + (size_t)i * HH + 8 * sl);
    float x[8];
    float part = 0.f;
#pragma unroll
    for (int q = 0; q < 8; q++) { x[q] = bf2f(hp[q]) + (Sts[q] + u[q]) * inv; part += x[q]; }
    // 32-lane butterfly: each half independently sums all 256 channels
#pragma unroll
    for (int off = 16; off; off >>= 1) part += __shfl_xor(part, off);
    float mu = part * (1.f / HH);
    float d[8];
    float vs = 0.f;
#pragma unroll
    for (int q = 0; q < 8; q++) { d[q] = x[q] - mu; vs += d[q] * d[q]; }
#pragma unroll
    for (int off = 16; off; off >>= 1) vs += __shfl_xor(vs, off);
    float rstd = rsqrtf(vs * (1.f / HH) + LN_EPS);
    float4 ga = *(const float4*)(lng + 8 * sl);
    float4 gb = *(const float4*)(lng + 8 * sl + 4);
    float4 ba = *(const float4*)(lnb + 8 * sl);
    float4 bb = *(const float4*)(lnb + 8 * sl + 4);
    float gg[8] = { ga.x, ga.y, ga.z, ga.w, gb.x, gb.y, gb.z, gb.w };
    float bv[8] = { ba.x, ba.y, ba.z, ba.w, bb.x, bb.y, bb.z, bb.w };
    float y[8];
#pragma unroll
    for (int q = 0; q < 8; q++) {
        float t = d[q] * rstd * gg[q] + bv[q];
        y[q] = t > 0.f ? t : __expf(t) - 1.f;
    }

    // stores: half 0 writes channels [8sl..8sl+3], half 1 writes [8sl+4..8sl+7]
    const int co = 8 * sl + 4 * half;
    if (houtb) {
        s16x4 yv;
#pragma unroll
        for (int q = 0; q < 4; q++) yv[q] = f2bf_bits(y[4 * half + q]);
        *(s16x4*)((short*)houtb + (size_t)i * HH + co) = yv;
    }
    if (houtf) {
        float4 yf = { y[4 * half], y[4 * half + 1], y[4 * half + 2], y[4 * half + 3] };
        *(float4*)(houtf + (size_t)i * HH + co) = yf;
    }

    if (last) {
        float4 wa = *(const float4*)(W_pool + 8 * sl);
        float4 wb = *(const float4*)(W_pool + 8 * sl + 4);
        float wp[8] = { wa.x, wa.y, wa.z, wa.w, wb.x, wb.y, wb.z, wb.w };
        float p = 0.f;
#pragma unroll
        for (int q = 0; q < 8; q++) p += y[q] * wp[q];
#pragma unroll
        for (int off = 16; off; off >>= 1) p += __shfl_xor(p, off);
        if (lane == 0) gate[i] = 1.f / (1.f + __expf(-(p + b_pool[0])));
    }
}

// ---------------- pooling: 256 blocks x 32 rows (256 atomics/address) ----------------
__global__ __launch_bounds__(256) void pool_kernel(const float* __restrict__ h, const float* __restrict__ gate,
                                                   float* __restrict__ emb) {
    int c = threadIdx.x;
    int r0 = blockIdx.x * 32;
    float acc = 0.f;
#pragma unroll
    for (int rr = 0; rr < 32; rr++) {
        int r = r0 + rr;
        acc += gate[r] * h[(size_t)r * HH + c];
    }
    atomicAdd(&emb[c], acc);
}

extern "C" void kernel_launch(void* const* d_in, const int* in_sizes, int n_in,
                              void* d_out, int out_size, void* d_ws, size_t ws_size,
                              hipStream_t stream) {
    const float* X      = (const float*)d_in[0];
    const int*   ei     = (const int*)d_in[1];
    const float* W_in   = (const float*)d_in[2];
    const float* b_in   = (const float*)d_in[3];
    const float* W_gat  = (const float*)d_in[4];
    const float* a_gat  = (const float*)d_in[5];
    const float* ln_g   = (const float*)d_in[6];
    const float* ln_b   = (const float*)d_in[7];
    const float* W_pool = (const float*)d_in[8];
    const float* b_pool = (const float*)d_in[9];
    float* out = (float*)d_out;

    // ws layout: bf16 region, then zero-init fp32/int block, then gate/buckets
    __hip_bfloat16* hb    = (__hip_bfloat16*)d_ws;            // NN*HH
    __hip_bfloat16* hwb   = hb + (size_t)NN * HH;             // NN*HH
    __hip_bfloat16* Wb_in = hwb + (size_t)NN * HH;            // HH*DIN
    __hip_bfloat16* Wgb   = Wb_in + (size_t)HH * DIN;         // 2*HH*HH
    __hip_bfloat16* Xb    = Wgb + (size_t)2 * HH * HH;        // NN*DIN
    float* zbase = (float*)(Xb + (size_t)NN * DIN);
    float* s1_0 = zbase;                 // NN
    float* s2_0 = s1_0 + NN;             // NN
    float* St_0 = s2_0 + NN;             // HH
    float* s1_1 = St_0 + HH;             // NN
    float* s2_1 = s1_1 + NN;             // NN
    float* St_1 = s2_1 + NN;             // HH
    int* cnt  = (int*)(St_1 + HH);       // NN  (zeroed in prep)
    float* gate = (float*)(cnt + NN);    // NN
    int* buck = (int*)(gate + NN);       // NN*CAP

    const int* src = ei;
    const int* tgt = ei + EE;
    float* emb = out + (size_t)NN * HH;

    // prep: zero + all bf16 conversions (one dispatch)
    int prep_quads = (NW1 + NW2 + NX) / 4;
    prep<<<(prep_quads + 255) / 256, 256, 0, stream>>>(W_in, Wb_in, W_gat, Wgb, X, Xb, zbase, emb);

    // adjacency buckets (one dispatch)
    fill_buckets<<<EE / 512, 256, 0, stream>>>(src, tgt, cnt, buck);

    // h = X @ W_in^T + b_in
    gemm_bb_bias<<<dim3(HH / 64, NN / 64), 256, 0, stream>>>(Xb, Wb_in, b_in, hb, HH, DIN);

    for (int ll = 0; ll < 2; ll++) {
        float* s1 = ll ? s1_1 : s1_0;
        float* s2 = ll ? s2_1 : s2_0;
        float* St = ll ? St_1 : St_0;
        const float* ag = a_gat + (size_t)ll * 2 * HH;
        gemm_bb_score<<<dim3(HH / 64, NN / 64), 256, 0, stream>>>(hb, Wgb + (size_t)ll * HH * HH, hwb,
                                                                  ag, ag + HH, s1, s2, St, HH, HH);
        gat_row<<<NN / 4, 256, 0, stream>>>(hb, hwb, cnt, buck, s1, s2, St,
                                            ln_g + (size_t)ll * HH, ln_b + (size_t)ll * HH,
                                            W_pool, b_pool,
                                            (ll == 1) ? out : nullptr,
                                            (ll == 0) ? hb : nullptr,
                                            gate, ll);
    }

    pool_kernel<<<NN / 32, 256, 0, stream>>>(out, gate, emb);
}